// Round 4
// baseline (174.665 us; speedup 1.0000x reference)
//
#include <hip/hip_runtime.h>
#include <math.h>

constexpr int MM = 50;    // members per group
constexpr int DD = 64;    // embedding dim
constexpr int HH = 16;    // attention hidden
constexpr int PH = 8;     // predict hidden
constexpr int WAVES_PER_BLOCK = 4;

// ============================================================================
// Kernel A: U  = user_table @ W1a                  (nU x 16)
//           Ib = item_table[item_inputs] @ W1b + b1 (B x 16)  <- batch rows only
// thread-per-row GEMV; branch is uniform per block.
// ============================================================================
__global__ __launch_bounds__(256) void precompute_kernel(
    const float* __restrict__ user_table,
    const float* __restrict__ item_table,
    const int*   __restrict__ item_inputs,
    const float* __restrict__ att_w1,   // [2D][H] row-major
    const float* __restrict__ att_b1,   // [H]
    float* __restrict__ U,
    float* __restrict__ Ib,
    int nU, int B, int userBlocks)
{
    const bool isU = (int)blockIdx.x < userBlocks;
    const float4* rp;
    const float*  w1;
    float* dst;
    float acc[HH];

    if (isU) {
        const int row = (int)blockIdx.x * 256 + (int)threadIdx.x;
        if (row >= nU) return;
        rp  = (const float4*)(user_table + (size_t)row * DD);
        w1  = att_w1;                       // member half of W1
        dst = U + (size_t)row * HH;
        #pragma unroll
        for (int j = 0; j < HH; ++j) acc[j] = 0.0f;
    } else {
        const int r = ((int)blockIdx.x - userBlocks) * 256 + (int)threadIdx.x;
        if (r >= B) return;
        const int item = item_inputs[r];    // coalesced
        rp  = (const float4*)(item_table + (size_t)item * DD);
        w1  = att_w1 + (size_t)DD * HH;     // item half of W1
        dst = Ib + (size_t)r * HH;
        #pragma unroll
        for (int j = 0; j < HH; ++j) acc[j] = att_b1[j];   // fold b1
    }

    #pragma unroll 4
    for (int d4 = 0; d4 < DD / 4; ++d4) {
        const float4 x = rp[d4];
        const float* w = w1 + (size_t)(d4 * 4) * HH;       // uniform -> s_load
        #pragma unroll
        for (int j = 0; j < HH; ++j) {
            acc[j] = fmaf(x.x, w[0 * HH + j], acc[j]);
            acc[j] = fmaf(x.y, w[1 * HH + j], acc[j]);
            acc[j] = fmaf(x.z, w[2 * HH + j], acc[j]);
            acc[j] = fmaf(x.w, w[3 * HH + j], acc[j]);
        }
    }

    float4* o4 = (float4*)dst;
    o4[0] = make_float4(acc[0],  acc[1],  acc[2],  acc[3]);
    o4[1] = make_float4(acc[4],  acc[5],  acc[6],  acc[7]);
    o4[2] = make_float4(acc[8],  acc[9],  acc[10], acc[11]);
    o4[3] = make_float4(acc[12], acc[13], acc[14], acc[15]);
}

// ============================================================================
// Kernel B: main. Wave per row. No LDS; all cross-lane via shfl/bpermute.
//   phase 1 (lane-per-member): score = relu(U[id]+Ib[b])·w2+b2, softmax
//   phase 2 (float4-per-lane, 4 reps x 16 d4): pool 4 member rows/pass via
//   dwordx4, rep-butterfly; group add; predict MLP; d4-butterfly; lane0 out.
// ============================================================================
__global__ __launch_bounds__(256) void agree_main(
    const int* __restrict__ group_inputs,
    const int* __restrict__ item_inputs,
    const int* __restrict__ member_ids,
    const int* __restrict__ member_lengths,
    const float* __restrict__ user_table,
    const float* __restrict__ item_table,
    const float* __restrict__ group_table,
    const float* __restrict__ att_w2,   // [H]
    const float* __restrict__ att_b2,   // [1]
    const float* __restrict__ pred_w1,  // [3D][8]
    const float* __restrict__ pred_b1,  // [8]
    const float* __restrict__ pred_w2,  // [8]
    const float* __restrict__ pred_b2,  // [1]
    const float* __restrict__ U,        // [nU][16]
    const float* __restrict__ Ib,       // [B][16], b1 folded
    float* __restrict__ out,
    int B)
{
    const int lane = threadIdx.x & 63;
    const int wave = threadIdx.x >> 6;
    const int b = blockIdx.x * WAVES_PER_BLOCK + wave;
    if (b >= B) return;

    const int my_m  = (lane < MM) ? lane : (MM - 1);
    const int my_id = member_ids[b * MM + my_m];            // coalesced
    const int len   = member_lengths[b];                    // uniform

    // ---- phase 1: attention score, lane-per-member
    const float4* up = (const float4*)(U + (size_t)my_id * HH); // 64B/lane gather
    const float4 u0 = up[0], u1 = up[1], u2 = up[2], u3 = up[3];
    const float* ib = Ib + (size_t)b * HH;                  // uniform -> s_load

    float score = att_b2[0];
    {
        const float uu[HH] = { u0.x,u0.y,u0.z,u0.w, u1.x,u1.y,u1.z,u1.w,
                               u2.x,u2.y,u2.z,u2.w, u3.x,u3.y,u3.z,u3.w };
        #pragma unroll
        for (int j = 0; j < HH; ++j)
            score = fmaf(fmaxf(uu[j] + ib[j], 0.0f), att_w2[j], score);
    }

    const bool valid = (lane < MM) && (lane <= len);
    score = valid ? score : -INFINITY;

    // softmax over members (member 0 always valid since len>=0)
    float mx = score;
    #pragma unroll
    for (int off = 32; off > 0; off >>= 1) mx = fmaxf(mx, __shfl_xor(mx, off, 64));
    const float e = valid ? __expf(score - mx) : 0.0f;
    float sum = e;
    #pragma unroll
    for (int off = 32; off > 0; off >>= 1) sum += __shfl_xor(sum, off, 64);
    const float wnorm = e / sum;   // 0 for invalid lanes

    // ---- phase 2: weighted pool in float4-per-lane layout
    const int d4  = lane & 15;     // which float4 of the 64-dim row
    const int rep = lane >> 4;     // 4 members handled per pass
    const int mcnt   = (len < MM - 1 ? len : MM - 1) + 1;   // uniform in [1,50]
    const int passes = (mcnt + 3) >> 2;                     // <= 13

    float4 g4 = make_float4(0.f, 0.f, 0.f, 0.f);
    int pass = 0;
    for (; pass + 2 <= passes; pass += 2) {                 // 8 members in flight
        const int m0 = pass * 4 + rep;
        const int m1 = m0 + 4;
        const float w0 = __shfl(wnorm, m0, 64);
        const int   i0 = __shfl(my_id, m0, 64);
        const float w1 = __shfl(wnorm, m1, 64);
        const int   i1 = __shfl(my_id, m1, 64);
        const float4 x0 = ((const float4*)(user_table + (size_t)i0 * DD))[d4];
        const float4 x1 = ((const float4*)(user_table + (size_t)i1 * DD))[d4];
        g4.x = fmaf(w0, x0.x, g4.x); g4.y = fmaf(w0, x0.y, g4.y);
        g4.z = fmaf(w0, x0.z, g4.z); g4.w = fmaf(w0, x0.w, g4.w);
        g4.x = fmaf(w1, x1.x, g4.x); g4.y = fmaf(w1, x1.y, g4.y);
        g4.z = fmaf(w1, x1.z, g4.z); g4.w = fmaf(w1, x1.w, g4.w);
    }
    if (pass < passes) {
        const int m0 = pass * 4 + rep;                      // <= 51 < 64
        const float w0 = __shfl(wnorm, m0, 64);             // 0 beyond len
        const int   i0 = __shfl(my_id, m0, 64);
        const float4 x0 = ((const float4*)(user_table + (size_t)i0 * DD))[d4];
        g4.x = fmaf(w0, x0.x, g4.x); g4.y = fmaf(w0, x0.y, g4.y);
        g4.z = fmaf(w0, x0.z, g4.z); g4.w = fmaf(w0, x0.w, g4.w);
    }
    // reduce over the 4 reps -> every lane holds pooled float4 for dims [4*d4,4*d4+4)
    #pragma unroll
    for (int off = 16; off <= 32; off <<= 1) {
        g4.x += __shfl_xor(g4.x, off, 64);
        g4.y += __shfl_xor(g4.y, off, 64);
        g4.z += __shfl_xor(g4.z, off, 64);
        g4.w += __shfl_xor(g4.w, off, 64);
    }

    // group + item rows in the same layout (16B/lane, L1/L2-hot)
    const int gid      = group_inputs[b];                   // uniform
    const int item_idx = item_inputs[b];                    // uniform
    const float4 gr  = ((const float4*)(group_table + (size_t)gid * DD))[d4];
    const float4 it4 = ((const float4*)(item_table + (size_t)item_idx * DD))[d4];
    g4.x += gr.x; g4.y += gr.y; g4.z += gr.z; g4.w += gr.w;
    const float4 e4 = make_float4(g4.x * it4.x, g4.y * it4.y,
                                  g4.z * it4.z, g4.w * it4.w);

    // ---- predict MLP: new_e = [elem, g, item] (192 -> 8 -> 1), float4 layout
    float p[PH];
    #pragma unroll
    for (int j = 0; j < PH; ++j) p[j] = 0.0f;
    {
        const float* wa = pred_w1 + (size_t)(4 * d4) * PH;            // rows 4d4..+3
        const float* wb = pred_w1 + (size_t)(DD + 4 * d4) * PH;
        const float* wc = pred_w1 + (size_t)(2 * DD + 4 * d4) * PH;
        const float ev[4] = { e4.x, e4.y, e4.z, e4.w };
        const float gv[4] = { g4.x, g4.y, g4.z, g4.w };
        const float iv[4] = { it4.x, it4.y, it4.z, it4.w };
        #pragma unroll
        for (int k = 0; k < 4; ++k) {
            #pragma unroll
            for (int j = 0; j < PH; ++j) {
                p[j] = fmaf(ev[k], wa[k * PH + j],
                       fmaf(gv[k], wb[k * PH + j],
                       fmaf(iv[k], wc[k * PH + j], p[j])));
            }
        }
    }
    // reduce over the 16 d4 groups (reps computed identical partials)
    #pragma unroll
    for (int off = 1; off <= 8; off <<= 1) {
        #pragma unroll
        for (int j = 0; j < PH; ++j) p[j] += __shfl_xor(p[j], off, 64);
    }

    if (lane == 0) {
        float acc = pred_b2[0];
        #pragma unroll
        for (int j = 0; j < PH; ++j)
            acc = fmaf(fmaxf(p[j] + pred_b1[j], 0.0f), pred_w2[j], acc);
        out[b] = 1.0f / (1.0f + __expf(-acc));
    }
}

// ============================================================================
// Fallback if ws too small (self-contained, round-2 structure)
// ============================================================================
__global__ __launch_bounds__(256) void agree_fallback(
    const int* __restrict__ group_inputs,
    const int* __restrict__ item_inputs,
    const int* __restrict__ member_ids,
    const int* __restrict__ member_lengths,
    const float* __restrict__ user_table,
    const float* __restrict__ item_table,
    const float* __restrict__ group_table,
    const float* __restrict__ att_w1,
    const float* __restrict__ att_b1,
    const float* __restrict__ att_w2,
    const float* __restrict__ att_b2,
    const float* __restrict__ pred_w1,
    const float* __restrict__ pred_b1,
    const float* __restrict__ pred_w2,
    const float* __restrict__ pred_b2,
    float* __restrict__ out,
    int B)
{
    __shared__ float lds_wt[WAVES_PER_BLOCK][MM];
    __shared__ int   lds_id[WAVES_PER_BLOCK][MM];

    const int lane = threadIdx.x & 63;
    const int wave = threadIdx.x >> 6;
    const int b = blockIdx.x * WAVES_PER_BLOCK + wave;
    if (b >= B) return;

    const int my_m = (lane < MM) ? lane : (MM - 1);
    const int my_id = member_ids[b * MM + my_m];
    if (lane < MM) lds_id[wave][lane] = my_id;

    const int item_idx = item_inputs[b];
    const float item_d = item_table[(size_t)item_idx * DD + lane];

    float h[HH];
    {
        const float* w1row = att_w1 + (size_t)(DD + lane) * HH;
        #pragma unroll
        for (int j = 0; j < HH; ++j) h[j] = item_d * w1row[j];
        #pragma unroll
        for (int off = 32; off > 0; off >>= 1) {
            #pragma unroll
            for (int j = 0; j < HH; ++j) h[j] += __shfl_xor(h[j], off, 64);
        }
        #pragma unroll
        for (int j = 0; j < HH; ++j) h[j] += att_b1[j];
    }

    const float* myrow = user_table + (size_t)my_id * DD;
    #pragma unroll 4
    for (int d4 = 0; d4 < DD / 4; ++d4) {
        const float4 x = ((const float4*)myrow)[d4];
        const float* w1d = att_w1 + (size_t)(d4 * 4) * HH;
        #pragma unroll
        for (int j = 0; j < HH; ++j) {
            h[j] = fmaf(x.x, w1d[0 * HH + j], h[j]);
            h[j] = fmaf(x.y, w1d[1 * HH + j], h[j]);
            h[j] = fmaf(x.z, w1d[2 * HH + j], h[j]);
            h[j] = fmaf(x.w, w1d[3 * HH + j], h[j]);
        }
    }

    float score = att_b2[0];
    #pragma unroll
    for (int j = 0; j < HH; ++j) score = fmaf(fmaxf(h[j], 0.0f), att_w2[j], score);

    const int len = member_lengths[b];
    const bool valid = (lane < MM) && (lane <= len);
    score = valid ? score : -INFINITY;

    float mx = score;
    #pragma unroll
    for (int off = 32; off > 0; off >>= 1) mx = fmaxf(mx, __shfl_xor(mx, off, 64));
    float e = valid ? __expf(score - mx) : 0.0f;
    float sum = e;
    #pragma unroll
    for (int off = 32; off > 0; off >>= 1) sum += __shfl_xor(sum, off, 64);
    if (lane < MM) lds_wt[wave][lane] = e / sum;
    __builtin_amdgcn_s_waitcnt(0);

    const int mcnt = (len < MM - 1 ? len : MM - 1) + 1;
    float g = 0.0f;
    #pragma unroll 2
    for (int m = 0; m < mcnt; ++m) {
        g = fmaf(lds_wt[wave][m],
                 user_table[(size_t)lds_id[wave][m] * DD + lane], g);
    }
    const int gid = group_inputs[b];
    g += group_table[(size_t)gid * DD + lane];

    const float elem = g * item_d;
    float p[PH];
    {
        const float* pa = pred_w1 + (size_t)lane * PH;
        const float* pb = pred_w1 + (size_t)(DD + lane) * PH;
        const float* pc = pred_w1 + (size_t)(2 * DD + lane) * PH;
        #pragma unroll
        for (int j = 0; j < PH; ++j)
            p[j] = fmaf(elem, pa[j], fmaf(g, pb[j], item_d * pc[j]));
    }
    #pragma unroll
    for (int off = 32; off > 0; off >>= 1) {
        #pragma unroll
        for (int j = 0; j < PH; ++j) p[j] += __shfl_xor(p[j], off, 64);
    }

    if (lane == 0) {
        float acc = pred_b2[0];
        #pragma unroll
        for (int j = 0; j < PH; ++j)
            acc = fmaf(fmaxf(p[j] + pred_b1[j], 0.0f), pred_w2[j], acc);
        out[b] = 1.0f / (1.0f + __expf(-acc));
    }
}

extern "C" void kernel_launch(void* const* d_in, const int* in_sizes, int n_in,
                              void* d_out, int out_size, void* d_ws, size_t ws_size,
                              hipStream_t stream) {
    const int*   group_inputs   = (const int*)d_in[0];
    const int*   item_inputs    = (const int*)d_in[1];
    const int*   member_ids     = (const int*)d_in[2];
    const int*   member_lengths = (const int*)d_in[3];
    const float* user_table     = (const float*)d_in[4];
    const float* item_table     = (const float*)d_in[5];
    const float* group_table    = (const float*)d_in[6];
    const float* att_w1         = (const float*)d_in[7];
    const float* att_b1         = (const float*)d_in[8];
    const float* att_w2         = (const float*)d_in[9];
    const float* att_b2         = (const float*)d_in[10];
    const float* pred_w1        = (const float*)d_in[11];
    const float* pred_b1        = (const float*)d_in[12];
    const float* pred_w2        = (const float*)d_in[13];
    const float* pred_b2        = (const float*)d_in[14];
    float* out = (float*)d_out;

    const int B  = in_sizes[0];
    const int nU = in_sizes[4] / DD;
    const size_t need = ((size_t)nU + (size_t)B) * HH * sizeof(float);
    const int blocks = (B + WAVES_PER_BLOCK - 1) / WAVES_PER_BLOCK;

    if (ws_size >= need) {
        float* U  = (float*)d_ws;
        float* Ib = U + (size_t)nU * HH;
        const int userBlocks = (nU + 255) / 256;
        const int itemBlocks = (B + 255) / 256;
        precompute_kernel<<<userBlocks + itemBlocks, 256, 0, stream>>>(
            user_table, item_table, item_inputs, att_w1, att_b1,
            U, Ib, nU, B, userBlocks);
        agree_main<<<blocks, 256, 0, stream>>>(
            group_inputs, item_inputs, member_ids, member_lengths,
            user_table, item_table, group_table,
            att_w2, att_b2, pred_w1, pred_b1, pred_w2, pred_b2,
            U, Ib, out, B);
    } else {
        agree_fallback<<<blocks, 256, 0, stream>>>(
            group_inputs, item_inputs, member_ids, member_lengths,
            user_table, item_table, group_table,
            att_w1, att_b1, att_w2, att_b2,
            pred_w1, pred_b1, pred_w2, pred_b2,
            out, B);
    }
}

// Round 5
// 150.912 us; speedup vs baseline: 1.1574x; 1.1574x over previous
//
#include <hip/hip_runtime.h>
#include <math.h>

constexpr int MM = 50;    // members per group
constexpr int DD = 64;    // embedding dim
constexpr int HH = 16;    // attention hidden
constexpr int PH = 8;     // predict hidden

// ============================================================================
// Kernel A: U  = user_table @ W1a                   (nU x 16)
//           Ib = item_table[item_inputs] @ W1b + b1 (B x 16)
// thread-per-row GEMV; branch uniform per block.
// ============================================================================
__global__ __launch_bounds__(256) void precompute_kernel(
    const float* __restrict__ user_table,
    const float* __restrict__ item_table,
    const int*   __restrict__ item_inputs,
    const float* __restrict__ att_w1,   // [2D][H] row-major
    const float* __restrict__ att_b1,   // [H]
    float* __restrict__ U,
    float* __restrict__ Ib,
    int nU, int B, int userBlocks)
{
    const bool isU = (int)blockIdx.x < userBlocks;
    const float4* rp;
    const float*  w1;
    float* dst;
    float acc[HH];

    if (isU) {
        const int row = (int)blockIdx.x * 256 + (int)threadIdx.x;
        if (row >= nU) return;
        rp  = (const float4*)(user_table + (size_t)row * DD);
        w1  = att_w1;
        dst = U + (size_t)row * HH;
        #pragma unroll
        for (int j = 0; j < HH; ++j) acc[j] = 0.0f;
    } else {
        const int r = ((int)blockIdx.x - userBlocks) * 256 + (int)threadIdx.x;
        if (r >= B) return;
        const int item = item_inputs[r];
        rp  = (const float4*)(item_table + (size_t)item * DD);
        w1  = att_w1 + (size_t)DD * HH;
        dst = Ib + (size_t)r * HH;
        #pragma unroll
        for (int j = 0; j < HH; ++j) acc[j] = att_b1[j];
    }

    #pragma unroll 4
    for (int d4 = 0; d4 < DD / 4; ++d4) {
        const float4 x = rp[d4];
        const float* w = w1 + (size_t)(d4 * 4) * HH;       // uniform -> s_load
        #pragma unroll
        for (int j = 0; j < HH; ++j) {
            acc[j] = fmaf(x.x, w[0 * HH + j], acc[j]);
            acc[j] = fmaf(x.y, w[1 * HH + j], acc[j]);
            acc[j] = fmaf(x.z, w[2 * HH + j], acc[j]);
            acc[j] = fmaf(x.w, w[3 * HH + j], acc[j]);
        }
    }

    float4* o4 = (float4*)dst;
    o4[0] = make_float4(acc[0],  acc[1],  acc[2],  acc[3]);
    o4[1] = make_float4(acc[4],  acc[5],  acc[6],  acc[7]);
    o4[2] = make_float4(acc[8],  acc[9],  acc[10], acc[11]);
    o4[3] = make_float4(acc[12], acc[13], acc[14], acc[15]);
}

// ============================================================================
// Kernel B: block-per-row. 4 waves cooperate on one b.
//  - phase 1 (all waves, redundant): score = relu(U[id]+Ib[b])·w2+b2, softmax
//    -> every wave holds wnorm (lane-per-member) in registers; no broadcast.
//  - phase 2: wave wv pools members m = wv+4k. Shuffles issued before loads;
//    7 (+6) independent coalesced row loads in flight per wave.
//  - LDS 3-partial reduce; wave 0 runs predict MLP.
// ============================================================================
__global__ __launch_bounds__(256) void agree_block(
    const int* __restrict__ group_inputs,
    const int* __restrict__ item_inputs,
    const int* __restrict__ member_ids,
    const int* __restrict__ member_lengths,
    const float* __restrict__ user_table,
    const float* __restrict__ item_table,
    const float* __restrict__ group_table,
    const float* __restrict__ att_w2,   // [H]
    const float* __restrict__ att_b2,   // [1]
    const float* __restrict__ pred_w1,  // [3D][8]
    const float* __restrict__ pred_b1,  // [8]
    const float* __restrict__ pred_w2,  // [8]
    const float* __restrict__ pred_b2,  // [1]
    const float* __restrict__ U,        // [nU][16]
    const float* __restrict__ Ib,       // [B][16], b1 folded
    float* __restrict__ out)
{
    __shared__ float lds_part[3][DD];   // waves 1..3 partial pools

    const int lane = threadIdx.x & 63;
    const int wv   = threadIdx.x >> 6;
    const int b    = blockIdx.x;

    const int my_m  = (lane < MM) ? lane : (MM - 1);
    const int my_id = member_ids[b * MM + my_m];            // coalesced, L1-shared
    const int len   = member_lengths[b];                    // uniform
    const int item_idx = item_inputs[b];                    // uniform
    const int gid      = group_inputs[b];                   // uniform

    // ---- phase 1: attention score (redundant per wave; U rows L1-hot for 3/4)
    const float4* up = (const float4*)(U + (size_t)my_id * HH);
    const float4 u0 = up[0], u1 = up[1], u2 = up[2], u3 = up[3];
    const float* ib = Ib + (size_t)b * HH;                  // uniform -> s_load

    float score = att_b2[0];
    {
        const float uu[HH] = { u0.x,u0.y,u0.z,u0.w, u1.x,u1.y,u1.z,u1.w,
                               u2.x,u2.y,u2.z,u2.w, u3.x,u3.y,u3.z,u3.w };
        #pragma unroll
        for (int j = 0; j < HH; ++j)
            score = fmaf(fmaxf(uu[j] + ib[j], 0.0f), att_w2[j], score);
    }

    const bool valid = (lane < MM) && (lane <= len);
    score = valid ? score : -INFINITY;

    float mx = score;
    #pragma unroll
    for (int off = 32; off > 0; off >>= 1) mx = fmaxf(mx, __shfl_xor(mx, off, 64));
    const float e = valid ? __expf(score - mx) : 0.0f;
    float sum = e;
    #pragma unroll
    for (int off = 32; off > 0; off >>= 1) sum += __shfl_xor(sum, off, 64);
    const float wnorm = e / sum;    // 0 for m>len and lanes>=50

    // issue the rows needed post-reduce early (in flight during the pool)
    const float item_d = item_table[(size_t)item_idx * DD + lane];
    const float grp_d  = group_table[(size_t)gid * DD + lane];

    // ---- phase 2: pool. wave wv handles m = wv + 4k, k = 0..12 (m <= 51).
    // wnorm==0 beyond len / beyond member 49 makes extra slots harmless.
    const int mcnt = (len < MM - 1 ? len : MM - 1) + 1;     // [1,50]
    float gw = 0.0f;
    {
        // chunk A: k = 0..6 — shuffles first, then 7 independent row loads
        float w[7]; int id[7]; float x[7];
        #pragma unroll
        for (int k = 0; k < 7; ++k) {
            const int m = wv + 4 * k;                       // <= 27, wave-uniform
            w[k]  = __shfl(wnorm, m, 64);
            id[k] = __shfl(my_id, m, 64);
        }
        #pragma unroll
        for (int k = 0; k < 7; ++k)
            x[k] = user_table[(size_t)id[k] * DD + lane];   // 256B coalesced row
        #pragma unroll
        for (int k = 0; k < 7; ++k) gw = fmaf(w[k], x[k], gw);
    }
    if (wv + 28 < mcnt) {                                   // wave-uniform branch
        // chunk B: k = 7..12 (m = wv+28 .. wv+48 <= 51)
        float w[6]; int id[6]; float x[6];
        #pragma unroll
        for (int k = 0; k < 6; ++k) {
            const int m = wv + 4 * (k + 7);
            w[k]  = __shfl(wnorm, m, 64);
            id[k] = __shfl(my_id, m, 64);
        }
        #pragma unroll
        for (int k = 0; k < 6; ++k)
            x[k] = user_table[(size_t)id[k] * DD + lane];
        #pragma unroll
        for (int k = 0; k < 6; ++k) gw = fmaf(w[k], x[k], gw);
    }

    // ---- cross-wave reduce (3 partials through LDS)
    if (wv) lds_part[wv - 1][lane] = gw;
    __syncthreads();
    if (wv) return;

    float g = gw + lds_part[0][lane] + lds_part[1][lane] + lds_part[2][lane];
    g += grp_d;

    // ---- predict MLP: new_e = [g*item, g, item] (192 -> 8 -> 1), lane-per-d
    const float elem = g * item_d;
    float p[PH];
    {
        const float* pa = pred_w1 + (size_t)lane * PH;            // L1-hot
        const float* pb = pred_w1 + (size_t)(DD + lane) * PH;
        const float* pc = pred_w1 + (size_t)(2 * DD + lane) * PH;
        #pragma unroll
        for (int j = 0; j < PH; ++j)
            p[j] = fmaf(elem, pa[j], fmaf(g, pb[j], item_d * pc[j]));
    }
    #pragma unroll
    for (int off = 32; off > 0; off >>= 1) {
        #pragma unroll
        for (int j = 0; j < PH; ++j) p[j] += __shfl_xor(p[j], off, 64);
    }

    if (lane == 0) {
        float acc = pred_b2[0];
        #pragma unroll
        for (int j = 0; j < PH; ++j)
            acc = fmaf(fmaxf(p[j] + pred_b1[j], 0.0f), pred_w2[j], acc);
        out[b] = 1.0f / (1.0f + __expf(-acc));
    }
}

// ============================================================================
// Fallback if ws too small (self-contained, round-2 structure)
// ============================================================================
__global__ __launch_bounds__(256) void agree_fallback(
    const int* __restrict__ group_inputs,
    const int* __restrict__ item_inputs,
    const int* __restrict__ member_ids,
    const int* __restrict__ member_lengths,
    const float* __restrict__ user_table,
    const float* __restrict__ item_table,
    const float* __restrict__ group_table,
    const float* __restrict__ att_w1,
    const float* __restrict__ att_b1,
    const float* __restrict__ att_w2,
    const float* __restrict__ att_b2,
    const float* __restrict__ pred_w1,
    const float* __restrict__ pred_b1,
    const float* __restrict__ pred_w2,
    const float* __restrict__ pred_b2,
    float* __restrict__ out,
    int B)
{
    __shared__ float lds_wt[4][MM];
    __shared__ int   lds_id[4][MM];

    const int lane = threadIdx.x & 63;
    const int wave = threadIdx.x >> 6;
    const int b = blockIdx.x * 4 + wave;
    if (b >= B) return;

    const int my_m = (lane < MM) ? lane : (MM - 1);
    const int my_id = member_ids[b * MM + my_m];
    if (lane < MM) lds_id[wave][lane] = my_id;

    const int item_idx = item_inputs[b];
    const float item_d = item_table[(size_t)item_idx * DD + lane];

    float h[HH];
    {
        const float* w1row = att_w1 + (size_t)(DD + lane) * HH;
        #pragma unroll
        for (int j = 0; j < HH; ++j) h[j] = item_d * w1row[j];
        #pragma unroll
        for (int off = 32; off > 0; off >>= 1) {
            #pragma unroll
            for (int j = 0; j < HH; ++j) h[j] += __shfl_xor(h[j], off, 64);
        }
        #pragma unroll
        for (int j = 0; j < HH; ++j) h[j] += att_b1[j];
    }

    const float* myrow = user_table + (size_t)my_id * DD;
    #pragma unroll 4
    for (int d4 = 0; d4 < DD / 4; ++d4) {
        const float4 x = ((const float4*)myrow)[d4];
        const float* w1d = att_w1 + (size_t)(d4 * 4) * HH;
        #pragma unroll
        for (int j = 0; j < HH; ++j) {
            h[j] = fmaf(x.x, w1d[0 * HH + j], h[j]);
            h[j] = fmaf(x.y, w1d[1 * HH + j], h[j]);
            h[j] = fmaf(x.z, w1d[2 * HH + j], h[j]);
            h[j] = fmaf(x.w, w1d[3 * HH + j], h[j]);
        }
    }

    float score = att_b2[0];
    #pragma unroll
    for (int j = 0; j < HH; ++j) score = fmaf(fmaxf(h[j], 0.0f), att_w2[j], score);

    const int len = member_lengths[b];
    const bool valid = (lane < MM) && (lane <= len);
    score = valid ? score : -INFINITY;

    float mx = score;
    #pragma unroll
    for (int off = 32; off > 0; off >>= 1) mx = fmaxf(mx, __shfl_xor(mx, off, 64));
    float e = valid ? __expf(score - mx) : 0.0f;
    float sum = e;
    #pragma unroll
    for (int off = 32; off > 0; off >>= 1) sum += __shfl_xor(sum, off, 64);
    if (lane < MM) lds_wt[wave][lane] = e / sum;
    __builtin_amdgcn_s_waitcnt(0);

    const int mcnt = (len < MM - 1 ? len : MM - 1) + 1;
    float g = 0.0f;
    #pragma unroll 2
    for (int m = 0; m < mcnt; ++m) {
        g = fmaf(lds_wt[wave][m],
                 user_table[(size_t)lds_id[wave][m] * DD + lane], g);
    }
    const int gid = group_inputs[b];
    g += group_table[(size_t)gid * DD + lane];

    const float elem = g * item_d;
    float p[PH];
    {
        const float* pa = pred_w1 + (size_t)lane * PH;
        const float* pb = pred_w1 + (size_t)(DD + lane) * PH;
        const float* pc = pred_w1 + (size_t)(2 * DD + lane) * PH;
        #pragma unroll
        for (int j = 0; j < PH; ++j)
            p[j] = fmaf(elem, pa[j], fmaf(g, pb[j], item_d * pc[j]));
    }
    #pragma unroll
    for (int off = 32; off > 0; off >>= 1) {
        #pragma unroll
        for (int j = 0; j < PH; ++j) p[j] += __shfl_xor(p[j], off, 64);
    }

    if (lane == 0) {
        float acc = pred_b2[0];
        #pragma unroll
        for (int j = 0; j < PH; ++j)
            acc = fmaf(fmaxf(p[j] + pred_b1[j], 0.0f), pred_w2[j], acc);
        out[b] = 1.0f / (1.0f + __expf(-acc));
    }
}

extern "C" void kernel_launch(void* const* d_in, const int* in_sizes, int n_in,
                              void* d_out, int out_size, void* d_ws, size_t ws_size,
                              hipStream_t stream) {
    const int*   group_inputs   = (const int*)d_in[0];
    const int*   item_inputs    = (const int*)d_in[1];
    const int*   member_ids     = (const int*)d_in[2];
    const int*   member_lengths = (const int*)d_in[3];
    const float* user_table     = (const float*)d_in[4];
    const float* item_table     = (const float*)d_in[5];
    const float* group_table    = (const float*)d_in[6];
    const float* att_w1         = (const float*)d_in[7];
    const float* att_b1         = (const float*)d_in[8];
    const float* att_w2         = (const float*)d_in[9];
    const float* att_b2         = (const float*)d_in[10];
    const float* pred_w1        = (const float*)d_in[11];
    const float* pred_b1        = (const float*)d_in[12];
    const float* pred_w2        = (const float*)d_in[13];
    const float* pred_b2        = (const float*)d_in[14];
    float* out = (float*)d_out;

    const int B  = in_sizes[0];
    const int nU = in_sizes[4] / DD;
    const size_t need = ((size_t)nU + (size_t)B) * HH * sizeof(float);

    if (ws_size >= need) {
        float* U  = (float*)d_ws;
        float* Ib = U + (size_t)nU * HH;
        const int userBlocks = (nU + 255) / 256;
        const int itemBlocks = (B + 255) / 256;
        precompute_kernel<<<userBlocks + itemBlocks, 256, 0, stream>>>(
            user_table, item_table, item_inputs, att_w1, att_b1,
            U, Ib, nU, B, userBlocks);
        agree_block<<<B, 256, 0, stream>>>(
            group_inputs, item_inputs, member_ids, member_lengths,
            user_table, item_table, group_table,
            att_w2, att_b2, pred_w1, pred_b1, pred_w2, pred_b2,
            U, Ib, out);
    } else {
        const int blocks = (B + 3) / 4;
        agree_fallback<<<blocks, 256, 0, stream>>>(
            group_inputs, item_inputs, member_ids, member_lengths,
            user_table, item_table, group_table,
            att_w1, att_b1, att_w2, att_b2,
            pred_w1, pred_b1, pred_w2, pred_b2,
            out, B);
    }
}

// Round 6
// 146.022 us; speedup vs baseline: 1.1962x; 1.0335x over previous
//
#include <hip/hip_runtime.h>
#include <math.h>

constexpr int MM = 50;    // members per group
constexpr int DD = 64;    // embedding dim
constexpr int HH = 16;    // attention hidden
constexpr int PH = 8;     // predict hidden
constexpr int WAVES_PER_BLOCK = 4;
constexpr int SLOTS = 56; // 7 chunks x 8, zero-padded past member 49

// ============================================================================
// Kernel A: U  = user_table @ W1a                   (nU x 16)
//           Ib = item_table[item_inputs] @ W1b + b1 (B x 16)
// ============================================================================
__global__ __launch_bounds__(256) void precompute_kernel(
    const float* __restrict__ user_table,
    const float* __restrict__ item_table,
    const int*   __restrict__ item_inputs,
    const float* __restrict__ att_w1,   // [2D][H] row-major
    const float* __restrict__ att_b1,   // [H]
    float* __restrict__ U,
    float* __restrict__ Ib,
    int nU, int B, int userBlocks)
{
    const bool isU = (int)blockIdx.x < userBlocks;
    const float4* rp;
    const float*  w1;
    float* dst;
    float acc[HH];

    if (isU) {
        const int row = (int)blockIdx.x * 256 + (int)threadIdx.x;
        if (row >= nU) return;
        rp  = (const float4*)(user_table + (size_t)row * DD);
        w1  = att_w1;
        dst = U + (size_t)row * HH;
        #pragma unroll
        for (int j = 0; j < HH; ++j) acc[j] = 0.0f;
    } else {
        const int r = ((int)blockIdx.x - userBlocks) * 256 + (int)threadIdx.x;
        if (r >= B) return;
        const int item = item_inputs[r];
        rp  = (const float4*)(item_table + (size_t)item * DD);
        w1  = att_w1 + (size_t)DD * HH;
        dst = Ib + (size_t)r * HH;
        #pragma unroll
        for (int j = 0; j < HH; ++j) acc[j] = att_b1[j];
    }

    #pragma unroll 4
    for (int d4 = 0; d4 < DD / 4; ++d4) {
        const float4 x = rp[d4];
        const float* w = w1 + (size_t)(d4 * 4) * HH;       // uniform -> s_load
        #pragma unroll
        for (int j = 0; j < HH; ++j) {
            acc[j] = fmaf(x.x, w[0 * HH + j], acc[j]);
            acc[j] = fmaf(x.y, w[1 * HH + j], acc[j]);
            acc[j] = fmaf(x.z, w[2 * HH + j], acc[j]);
            acc[j] = fmaf(x.w, w[3 * HH + j], acc[j]);
        }
    }

    float4* o4 = (float4*)dst;
    o4[0] = make_float4(acc[0],  acc[1],  acc[2],  acc[3]);
    o4[1] = make_float4(acc[4],  acc[5],  acc[6],  acc[7]);
    o4[2] = make_float4(acc[8],  acc[9],  acc[10], acc[11]);
    o4[3] = make_float4(acc[12], acc[13], acc[14], acc[15]);
}

// ============================================================================
// Kernel B: wave-per-row. Phase 1 once per row (no redundancy, no barrier).
// Pool in chunks of 8: 8 broadcast ds_read_b64 -> 8 independent global loads
// in flight -> 8 FMAs. 32-bit indices keep addr-calc to ~2 VALU per load.
// ============================================================================
__global__ __launch_bounds__(256) void agree_main(
    const int* __restrict__ group_inputs,
    const int* __restrict__ item_inputs,
    const int* __restrict__ member_ids,
    const int* __restrict__ member_lengths,
    const float* __restrict__ user_table,
    const float* __restrict__ item_table,
    const float* __restrict__ group_table,
    const float* __restrict__ att_w2,   // [H]
    const float* __restrict__ att_b2,   // [1]
    const float* __restrict__ pred_w1,  // [3D][8]
    const float* __restrict__ pred_b1,  // [8]
    const float* __restrict__ pred_w2,  // [8]
    const float* __restrict__ pred_b2,  // [1]
    const float* __restrict__ U,        // [nU][16]
    const float* __restrict__ Ib,       // [B][16], b1 folded
    float* __restrict__ out,
    int B)
{
    __shared__ float2 pairs[WAVES_PER_BLOCK][SLOTS]; // (wnorm, id bits), 1792 B

    const int lane = threadIdx.x & 63;
    const int wv   = threadIdx.x >> 6;
    const int b    = blockIdx.x * WAVES_PER_BLOCK + wv;
    if (b >= B) return;

    const int my_m  = (lane < MM) ? lane : (MM - 1);
    const int my_id = member_ids[b * MM + my_m];            // coalesced
    const int len   = member_lengths[b];                    // uniform
    const int item_idx = item_inputs[b];                    // uniform
    const int gid      = group_inputs[b];                   // uniform

    // issue post-softmax rows early so they're in flight during phase 1
    const float item_d = item_table[(unsigned)(item_idx * DD + lane)];
    const float grp_d  = group_table[(unsigned)(gid * DD + lane)];

    // ---- phase 1: attention score, lane-per-member (computed ONCE per row)
    const float4* up = (const float4*)(U + ((size_t)(unsigned)my_id * HH));
    const float4 u0 = up[0], u1 = up[1], u2 = up[2], u3 = up[3];
    const float* ib = Ib + (size_t)b * HH;                  // uniform -> s_load

    float score = att_b2[0];
    {
        const float uu[HH] = { u0.x,u0.y,u0.z,u0.w, u1.x,u1.y,u1.z,u1.w,
                               u2.x,u2.y,u2.z,u2.w, u3.x,u3.y,u3.z,u3.w };
        #pragma unroll
        for (int j = 0; j < HH; ++j)
            score = fmaf(fmaxf(uu[j] + ib[j], 0.0f), att_w2[j], score);
    }

    const bool valid = (lane < MM) && (lane <= len);
    score = valid ? score : -INFINITY;

    // softmax over members (member 0 always valid)
    float mx = score;
    #pragma unroll
    for (int off = 32; off > 0; off >>= 1) mx = fmaxf(mx, __shfl_xor(mx, off, 64));
    const float e = valid ? __expf(score - mx) : 0.0f;
    float sum = e;
    #pragma unroll
    for (int off = 32; off > 0; off >>= 1) sum += __shfl_xor(sum, off, 64);
    const float wnorm = e / sum;    // 0 for invalid lanes (incl. 50..63)

    // stash (wnorm, id) pairs; slots 50..55 get wnorm=0 with a valid id
    if (lane < SLOTS) pairs[wv][lane] = make_float2(wnorm, __int_as_float(my_id));
    __builtin_amdgcn_s_waitcnt(0);  // drain own-wave LDS writes (no barrier)

    // ---- phase 2: weighted pool, chunks of 8 independent row loads
    const int mcnt   = (len < MM - 1 ? len : MM - 1) + 1;   // uniform in [1,50]
    const int chunks = (mcnt + 7) >> 3;                     // 1..7, uniform

    float g = 0.0f;
    for (int c = 0; c < chunks; ++c) {
        float2 q[8];
        #pragma unroll
        for (int k = 0; k < 8; ++k) q[k] = pairs[wv][c * 8 + k]; // broadcast reads
        float x[8];
        #pragma unroll
        for (int k = 0; k < 8; ++k) {
            const unsigned idx = (unsigned)(__float_as_int(q[k].y) * DD + lane);
            x[k] = user_table[idx];                         // 256B coalesced row
        }
        #pragma unroll
        for (int k = 0; k < 8; ++k) g = fmaf(q[k].x, x[k], g);
    }
    g += grp_d;

    // ---- predict MLP: new_e = [g*item, g, item] (192 -> 8 -> 1), lane-per-d
    const float elem = g * item_d;
    float p[PH];
    {
        const float* pa = pred_w1 + (size_t)lane * PH;      // L1-hot
        const float* pb = pred_w1 + (size_t)(DD + lane) * PH;
        const float* pc = pred_w1 + (size_t)(2 * DD + lane) * PH;
        #pragma unroll
        for (int j = 0; j < PH; ++j)
            p[j] = fmaf(elem, pa[j], fmaf(g, pb[j], item_d * pc[j]));
    }
    #pragma unroll
    for (int off = 32; off > 0; off >>= 1) {
        #pragma unroll
        for (int j = 0; j < PH; ++j) p[j] += __shfl_xor(p[j], off, 64);
    }

    if (lane == 0) {
        float acc = pred_b2[0];
        #pragma unroll
        for (int j = 0; j < PH; ++j)
            acc = fmaf(fmaxf(p[j] + pred_b1[j], 0.0f), pred_w2[j], acc);
        out[b] = 1.0f / (1.0f + __expf(-acc));
    }
}

// ============================================================================
// Fallback if ws too small (self-contained, round-2 structure)
// ============================================================================
__global__ __launch_bounds__(256) void agree_fallback(
    const int* __restrict__ group_inputs,
    const int* __restrict__ item_inputs,
    const int* __restrict__ member_ids,
    const int* __restrict__ member_lengths,
    const float* __restrict__ user_table,
    const float* __restrict__ item_table,
    const float* __restrict__ group_table,
    const float* __restrict__ att_w1,
    const float* __restrict__ att_b1,
    const float* __restrict__ att_w2,
    const float* __restrict__ att_b2,
    const float* __restrict__ pred_w1,
    const float* __restrict__ pred_b1,
    const float* __restrict__ pred_w2,
    const float* __restrict__ pred_b2,
    float* __restrict__ out,
    int B)
{
    __shared__ float lds_wt[4][MM];
    __shared__ int   lds_id[4][MM];

    const int lane = threadIdx.x & 63;
    const int wave = threadIdx.x >> 6;
    const int b = blockIdx.x * 4 + wave;
    if (b >= B) return;

    const int my_m = (lane < MM) ? lane : (MM - 1);
    const int my_id = member_ids[b * MM + my_m];
    if (lane < MM) lds_id[wave][lane] = my_id;

    const int item_idx = item_inputs[b];
    const float item_d = item_table[(size_t)item_idx * DD + lane];

    float h[HH];
    {
        const float* w1row = att_w1 + (size_t)(DD + lane) * HH;
        #pragma unroll
        for (int j = 0; j < HH; ++j) h[j] = item_d * w1row[j];
        #pragma unroll
        for (int off = 32; off > 0; off >>= 1) {
            #pragma unroll
            for (int j = 0; j < HH; ++j) h[j] += __shfl_xor(h[j], off, 64);
        }
        #pragma unroll
        for (int j = 0; j < HH; ++j) h[j] += att_b1[j];
    }

    const float* myrow = user_table + (size_t)my_id * DD;
    #pragma unroll 4
    for (int d4 = 0; d4 < DD / 4; ++d4) {
        const float4 x = ((const float4*)myrow)[d4];
        const float* w1d = att_w1 + (size_t)(d4 * 4) * HH;
        #pragma unroll
        for (int j = 0; j < HH; ++j) {
            h[j] = fmaf(x.x, w1d[0 * HH + j], h[j]);
            h[j] = fmaf(x.y, w1d[1 * HH + j], h[j]);
            h[j] = fmaf(x.z, w1d[2 * HH + j], h[j]);
            h[j] = fmaf(x.w, w1d[3 * HH + j], h[j]);
        }
    }

    float score = att_b2[0];
    #pragma unroll
    for (int j = 0; j < HH; ++j) score = fmaf(fmaxf(h[j], 0.0f), att_w2[j], score);

    const int len = member_lengths[b];
    const bool valid = (lane < MM) && (lane <= len);
    score = valid ? score : -INFINITY;

    float mx = score;
    #pragma unroll
    for (int off = 32; off > 0; off >>= 1) mx = fmaxf(mx, __shfl_xor(mx, off, 64));
    float e = valid ? __expf(score - mx) : 0.0f;
    float sum = e;
    #pragma unroll
    for (int off = 32; off > 0; off >>= 1) sum += __shfl_xor(sum, off, 64);
    if (lane < MM) lds_wt[wave][lane] = e / sum;
    __builtin_amdgcn_s_waitcnt(0);

    const int mcnt = (len < MM - 1 ? len : MM - 1) + 1;
    float g = 0.0f;
    #pragma unroll 2
    for (int m = 0; m < mcnt; ++m) {
        g = fmaf(lds_wt[wave][m],
                 user_table[(size_t)lds_id[wave][m] * DD + lane], g);
    }
    const int gid = group_inputs[b];
    g += group_table[(size_t)gid * DD + lane];

    const float elem = g * item_d;
    float p[PH];
    {
        const float* pa = pred_w1 + (size_t)lane * PH;
        const float* pb = pred_w1 + (size_t)(DD + lane) * PH;
        const float* pc = pred_w1 + (size_t)(2 * DD + lane) * PH;
        #pragma unroll
        for (int j = 0; j < PH; ++j)
            p[j] = fmaf(elem, pa[j], fmaf(g, pb[j], item_d * pc[j]));
    }
    #pragma unroll
    for (int off = 32; off > 0; off >>= 1) {
        #pragma unroll
        for (int j = 0; j < PH; ++j) p[j] += __shfl_xor(p[j], off, 64);
    }

    if (lane == 0) {
        float acc = pred_b2[0];
        #pragma unroll
        for (int j = 0; j < PH; ++j)
            acc = fmaf(fmaxf(p[j] + pred_b1[j], 0.0f), pred_w2[j], acc);
        out[b] = 1.0f / (1.0f + __expf(-acc));
    }
}

extern "C" void kernel_launch(void* const* d_in, const int* in_sizes, int n_in,
                              void* d_out, int out_size, void* d_ws, size_t ws_size,
                              hipStream_t stream) {
    const int*   group_inputs   = (const int*)d_in[0];
    const int*   item_inputs    = (const int*)d_in[1];
    const int*   member_ids     = (const int*)d_in[2];
    const int*   member_lengths = (const int*)d_in[3];
    const float* user_table     = (const float*)d_in[4];
    const float* item_table     = (const float*)d_in[5];
    const float* group_table    = (const float*)d_in[6];
    const float* att_w1         = (const float*)d_in[7];
    const float* att_b1         = (const float*)d_in[8];
    const float* att_w2         = (const float*)d_in[9];
    const float* att_b2         = (const float*)d_in[10];
    const float* pred_w1        = (const float*)d_in[11];
    const float* pred_b1        = (const float*)d_in[12];
    const float* pred_w2        = (const float*)d_in[13];
    const float* pred_b2        = (const float*)d_in[14];
    float* out = (float*)d_out;

    const int B  = in_sizes[0];
    const int nU = in_sizes[4] / DD;
    const size_t need = ((size_t)nU + (size_t)B) * HH * sizeof(float);
    const int blocks = (B + WAVES_PER_BLOCK - 1) / WAVES_PER_BLOCK;

    if (ws_size >= need) {
        float* U  = (float*)d_ws;
        float* Ib = U + (size_t)nU * HH;
        const int userBlocks = (nU + 255) / 256;
        const int itemBlocks = (B + 255) / 256;
        precompute_kernel<<<userBlocks + itemBlocks, 256, 0, stream>>>(
            user_table, item_table, item_inputs, att_w1, att_b1,
            U, Ib, nU, B, userBlocks);
        agree_main<<<blocks, 256, 0, stream>>>(
            group_inputs, item_inputs, member_ids, member_lengths,
            user_table, item_table, group_table,
            att_w2, att_b2, pred_w1, pred_b1, pred_w2, pred_b2,
            U, Ib, out, B);
    } else {
        agree_fallback<<<blocks, 256, 0, stream>>>(
            group_inputs, item_inputs, member_ids, member_lengths,
            user_table, item_table, group_table,
            att_w1, att_b1, att_w2, att_b2,
            pred_w1, pred_b1, pred_w2, pred_b2,
            out, B);
    }
}

// Round 7
// 145.248 us; speedup vs baseline: 1.2025x; 1.0053x over previous
//
#include <hip/hip_runtime.h>
#include <math.h>

constexpr int MM = 50;    // members per group
constexpr int DD = 64;    // embedding dim
constexpr int HH = 16;    // attention hidden
constexpr int PH = 8;     // predict hidden
constexpr int WAVES_PER_BLOCK = 4;
constexpr int SLOTS = 56; // 7 chunks x 8, zero-padded past member 49

// round-to-nearest-even fp32 -> bf16 (as uint16 in low bits)
__device__ __forceinline__ unsigned bf16rne(float f) {
    const unsigned u = __float_as_uint(f);
    return (u + 0x7FFFu + ((u >> 16) & 1u)) >> 16;
}

// ============================================================================
// Kernel A: U  = user_table @ W1a                   (nU x 16)  fp32
//           Ub = bf16(user_table)                   (nU x 64)  2B/elem
//           Ib = item_table[item_inputs] @ W1b + b1 (B x 16)   fp32
// thread-per-row GEMV; branch uniform per block.
// ============================================================================
__global__ __launch_bounds__(256) void precompute_kernel(
    const float* __restrict__ user_table,
    const float* __restrict__ item_table,
    const int*   __restrict__ item_inputs,
    const float* __restrict__ att_w1,   // [2D][H] row-major
    const float* __restrict__ att_b1,   // [H]
    float* __restrict__ U,
    float* __restrict__ Ib,
    unsigned short* __restrict__ Ub,    // bf16 user table copy
    int nU, int B, int userBlocks)
{
    const bool isU = (int)blockIdx.x < userBlocks;
    const float4* rp;
    const float*  w1;
    float* dst;
    float acc[HH];
    int row = 0;

    if (isU) {
        row = (int)blockIdx.x * 256 + (int)threadIdx.x;
        if (row >= nU) return;
        rp  = (const float4*)(user_table + (size_t)row * DD);
        w1  = att_w1;
        dst = U + (size_t)row * HH;
        #pragma unroll
        for (int j = 0; j < HH; ++j) acc[j] = 0.0f;
    } else {
        const int r = ((int)blockIdx.x - userBlocks) * 256 + (int)threadIdx.x;
        if (r >= B) return;
        const int item = item_inputs[r];
        rp  = (const float4*)(item_table + (size_t)item * DD);
        w1  = att_w1 + (size_t)DD * HH;
        dst = Ib + (size_t)r * HH;
        #pragma unroll
        for (int j = 0; j < HH; ++j) acc[j] = att_b1[j];
    }

    unsigned brow[DD / 2];              // packed bf16 row (users only)

    #pragma unroll 4
    for (int d4 = 0; d4 < DD / 4; ++d4) {
        const float4 x = rp[d4];
        const float* w = w1 + (size_t)(d4 * 4) * HH;       // uniform -> s_load
        #pragma unroll
        for (int j = 0; j < HH; ++j) {
            acc[j] = fmaf(x.x, w[0 * HH + j], acc[j]);
            acc[j] = fmaf(x.y, w[1 * HH + j], acc[j]);
            acc[j] = fmaf(x.z, w[2 * HH + j], acc[j]);
            acc[j] = fmaf(x.w, w[3 * HH + j], acc[j]);
        }
        brow[2 * d4]     = bf16rne(x.x) | (bf16rne(x.y) << 16);
        brow[2 * d4 + 1] = bf16rne(x.z) | (bf16rne(x.w) << 16);
    }

    float4* o4 = (float4*)dst;
    o4[0] = make_float4(acc[0],  acc[1],  acc[2],  acc[3]);
    o4[1] = make_float4(acc[4],  acc[5],  acc[6],  acc[7]);
    o4[2] = make_float4(acc[8],  acc[9],  acc[10], acc[11]);
    o4[3] = make_float4(acc[12], acc[13], acc[14], acc[15]);

    if (isU) {
        uint4* b4 = (uint4*)(Ub + (size_t)row * DD);       // 128B row
        #pragma unroll
        for (int i = 0; i < DD / 8; ++i)
            b4[i] = make_uint4(brow[4 * i], brow[4 * i + 1],
                               brow[4 * i + 2], brow[4 * i + 3]);
    }
}

// ============================================================================
// Kernel B: wave-per-row. Phase 1 once per row. Pool gathers read the bf16
// table copy (128B rows, half the HBM bytes of fp32).
// ============================================================================
__global__ __launch_bounds__(256) void agree_main(
    const int* __restrict__ group_inputs,
    const int* __restrict__ item_inputs,
    const int* __restrict__ member_ids,
    const int* __restrict__ member_lengths,
    const float* __restrict__ item_table,
    const float* __restrict__ group_table,
    const float* __restrict__ att_w2,   // [H]
    const float* __restrict__ att_b2,   // [1]
    const float* __restrict__ pred_w1,  // [3D][8]
    const float* __restrict__ pred_b1,  // [8]
    const float* __restrict__ pred_w2,  // [8]
    const float* __restrict__ pred_b2,  // [1]
    const float* __restrict__ U,        // [nU][16]
    const float* __restrict__ Ib,       // [B][16], b1 folded
    const unsigned short* __restrict__ Ub, // [nU][64] bf16
    float* __restrict__ out,
    int B)
{
    __shared__ float2 pairs[WAVES_PER_BLOCK][SLOTS]; // (wnorm, id bits), 1792 B

    const int lane = threadIdx.x & 63;
    const int wv   = threadIdx.x >> 6;
    const int b    = blockIdx.x * WAVES_PER_BLOCK + wv;
    if (b >= B) return;

    const int my_m  = (lane < MM) ? lane : (MM - 1);
    const int my_id = member_ids[b * MM + my_m];            // coalesced
    const int len   = member_lengths[b];                    // uniform
    const int item_idx = item_inputs[b];                    // uniform
    const int gid      = group_inputs[b];                   // uniform

    // issue post-softmax rows early so they're in flight during phase 1
    const float item_d = item_table[(unsigned)(item_idx * DD + lane)];
    const float grp_d  = group_table[(unsigned)(gid * DD + lane)];

    // ---- phase 1: attention score, lane-per-member (computed ONCE per row)
    const float4* up = (const float4*)(U + ((size_t)(unsigned)my_id * HH));
    const float4 u0 = up[0], u1 = up[1], u2 = up[2], u3 = up[3];
    const float* ib = Ib + (size_t)b * HH;                  // uniform -> s_load

    float score = att_b2[0];
    {
        const float uu[HH] = { u0.x,u0.y,u0.z,u0.w, u1.x,u1.y,u1.z,u1.w,
                               u2.x,u2.y,u2.z,u2.w, u3.x,u3.y,u3.z,u3.w };
        #pragma unroll
        for (int j = 0; j < HH; ++j)
            score = fmaf(fmaxf(uu[j] + ib[j], 0.0f), att_w2[j], score);
    }

    const bool valid = (lane < MM) && (lane <= len);
    score = valid ? score : -INFINITY;

    // softmax over members (member 0 always valid)
    float mx = score;
    #pragma unroll
    for (int off = 32; off > 0; off >>= 1) mx = fmaxf(mx, __shfl_xor(mx, off, 64));
    const float e = valid ? __expf(score - mx) : 0.0f;
    float sum = e;
    #pragma unroll
    for (int off = 32; off > 0; off >>= 1) sum += __shfl_xor(sum, off, 64);
    const float wnorm = e / sum;    // 0 for invalid lanes (incl. 50..63)

    // stash (wnorm, id) pairs; slots 50..55 get wnorm=0 with a valid id
    if (lane < SLOTS) pairs[wv][lane] = make_float2(wnorm, __int_as_float(my_id));
    __builtin_amdgcn_s_waitcnt(0);  // drain own-wave LDS writes (no barrier)

    // ---- phase 2: weighted pool from bf16 table, chunks of 8 loads in flight
    const int mcnt   = (len < MM - 1 ? len : MM - 1) + 1;   // uniform in [1,50]
    const int chunks = (mcnt + 7) >> 3;                     // 1..7, uniform

    float g = 0.0f;
    for (int c = 0; c < chunks; ++c) {
        float2 q[8];
        #pragma unroll
        for (int k = 0; k < 8; ++k) q[k] = pairs[wv][c * 8 + k]; // broadcast reads
        unsigned short xb[8];
        #pragma unroll
        for (int k = 0; k < 8; ++k) {
            const unsigned idx = (unsigned)(__float_as_int(q[k].y) * DD + lane);
            xb[k] = Ub[idx];                                // 128B coalesced bf16 row
        }
        #pragma unroll
        for (int k = 0; k < 8; ++k)
            g = fmaf(q[k].x, __uint_as_float((unsigned)xb[k] << 16), g);
    }
    g += grp_d;

    // ---- predict MLP: new_e = [g*item, g, item] (192 -> 8 -> 1), lane-per-d
    const float elem = g * item_d;
    float p[PH];
    {
        const float* pa = pred_w1 + (size_t)lane * PH;      // L1-hot
        const float* pb = pred_w1 + (size_t)(DD + lane) * PH;
        const float* pc = pred_w1 + (size_t)(2 * DD + lane) * PH;
        #pragma unroll
        for (int j = 0; j < PH; ++j)
            p[j] = fmaf(elem, pa[j], fmaf(g, pb[j], item_d * pc[j]));
    }
    #pragma unroll
    for (int off = 32; off > 0; off >>= 1) {
        #pragma unroll
        for (int j = 0; j < PH; ++j) p[j] += __shfl_xor(p[j], off, 64);
    }

    if (lane == 0) {
        float acc = pred_b2[0];
        #pragma unroll
        for (int j = 0; j < PH; ++j)
            acc = fmaf(fmaxf(p[j] + pred_b1[j], 0.0f), pred_w2[j], acc);
        out[b] = 1.0f / (1.0f + __expf(-acc));
    }
}

// ============================================================================
// Fallback if ws too small (self-contained, round-2 structure, full fp32)
// ============================================================================
__global__ __launch_bounds__(256) void agree_fallback(
    const int* __restrict__ group_inputs,
    const int* __restrict__ item_inputs,
    const int* __restrict__ member_ids,
    const int* __restrict__ member_lengths,
    const float* __restrict__ user_table,
    const float* __restrict__ item_table,
    const float* __restrict__ group_table,
    const float* __restrict__ att_w1,
    const float* __restrict__ att_b1,
    const float* __restrict__ att_w2,
    const float* __restrict__ att_b2,
    const float* __restrict__ pred_w1,
    const float* __restrict__ pred_b1,
    const float* __restrict__ pred_w2,
    const float* __restrict__ pred_b2,
    float* __restrict__ out,
    int B)
{
    __shared__ float lds_wt[4][MM];
    __shared__ int   lds_id[4][MM];

    const int lane = threadIdx.x & 63;
    const int wave = threadIdx.x >> 6;
    const int b = blockIdx.x * 4 + wave;
    if (b >= B) return;

    const int my_m = (lane < MM) ? lane : (MM - 1);
    const int my_id = member_ids[b * MM + my_m];
    if (lane < MM) lds_id[wave][lane] = my_id;

    const int item_idx = item_inputs[b];
    const float item_d = item_table[(size_t)item_idx * DD + lane];

    float h[HH];
    {
        const float* w1row = att_w1 + (size_t)(DD + lane) * HH;
        #pragma unroll
        for (int j = 0; j < HH; ++j) h[j] = item_d * w1row[j];
        #pragma unroll
        for (int off = 32; off > 0; off >>= 1) {
            #pragma unroll
            for (int j = 0; j < HH; ++j) h[j] += __shfl_xor(h[j], off, 64);
        }
        #pragma unroll
        for (int j = 0; j < HH; ++j) h[j] += att_b1[j];
    }

    const float* myrow = user_table + (size_t)my_id * DD;
    #pragma unroll 4
    for (int d4 = 0; d4 < DD / 4; ++d4) {
        const float4 x = ((const float4*)myrow)[d4];
        const float* w1d = att_w1 + (size_t)(d4 * 4) * HH;
        #pragma unroll
        for (int j = 0; j < HH; ++j) {
            h[j] = fmaf(x.x, w1d[0 * HH + j], h[j]);
            h[j] = fmaf(x.y, w1d[1 * HH + j], h[j]);
            h[j] = fmaf(x.z, w1d[2 * HH + j], h[j]);
            h[j] = fmaf(x.w, w1d[3 * HH + j], h[j]);
        }
    }

    float score = att_b2[0];
    #pragma unroll
    for (int j = 0; j < HH; ++j) score = fmaf(fmaxf(h[j], 0.0f), att_w2[j], score);

    const int len = member_lengths[b];
    const bool valid = (lane < MM) && (lane <= len);
    score = valid ? score : -INFINITY;

    float mx = score;
    #pragma unroll
    for (int off = 32; off > 0; off >>= 1) mx = fmaxf(mx, __shfl_xor(mx, off, 64));
    float e = valid ? __expf(score - mx) : 0.0f;
    float sum = e;
    #pragma unroll
    for (int off = 32; off > 0; off >>= 1) sum += __shfl_xor(sum, off, 64);
    if (lane < MM) lds_wt[wave][lane] = e / sum;
    __builtin_amdgcn_s_waitcnt(0);

    const int mcnt = (len < MM - 1 ? len : MM - 1) + 1;
    float g = 0.0f;
    #pragma unroll 2
    for (int m = 0; m < mcnt; ++m) {
        g = fmaf(lds_wt[wave][m],
                 user_table[(size_t)lds_id[wave][m] * DD + lane], g);
    }
    const int gid = group_inputs[b];
    g += group_table[(size_t)gid * DD + lane];

    const float elem = g * item_d;
    float p[PH];
    {
        const float* pa = pred_w1 + (size_t)lane * PH;
        const float* pb = pred_w1 + (size_t)(DD + lane) * PH;
        const float* pc = pred_w1 + (size_t)(2 * DD + lane) * PH;
        #pragma unroll
        for (int j = 0; j < PH; ++j)
            p[j] = fmaf(elem, pa[j], fmaf(g, pb[j], item_d * pc[j]));
    }
    #pragma unroll
    for (int off = 32; off > 0; off >>= 1) {
        #pragma unroll
        for (int j = 0; j < PH; ++j) p[j] += __shfl_xor(p[j], off, 64);
    }

    if (lane == 0) {
        float acc = pred_b2[0];
        #pragma unroll
        for (int j = 0; j < PH; ++j)
            acc = fmaf(fmaxf(p[j] + pred_b1[j], 0.0f), pred_w2[j], acc);
        out[b] = 1.0f / (1.0f + __expf(-acc));
    }
}

extern "C" void kernel_launch(void* const* d_in, const int* in_sizes, int n_in,
                              void* d_out, int out_size, void* d_ws, size_t ws_size,
                              hipStream_t stream) {
    const int*   group_inputs   = (const int*)d_in[0];
    const int*   item_inputs    = (const int*)d_in[1];
    const int*   member_ids     = (const int*)d_in[2];
    const int*   member_lengths = (const int*)d_in[3];
    const float* user_table     = (const float*)d_in[4];
    const float* item_table     = (const float*)d_in[5];
    const float* group_table    = (const float*)d_in[6];
    const float* att_w1         = (const float*)d_in[7];
    const float* att_b1         = (const float*)d_in[8];
    const float* att_w2         = (const float*)d_in[9];
    const float* att_b2         = (const float*)d_in[10];
    const float* pred_w1        = (const float*)d_in[11];
    const float* pred_b1        = (const float*)d_in[12];
    const float* pred_w2        = (const float*)d_in[13];
    const float* pred_b2        = (const float*)d_in[14];
    float* out = (float*)d_out;

    const int B  = in_sizes[0];
    const int nU = in_sizes[4] / DD;
    // layout in ws: U (nU*16 f32) | Ib (B*16 f32) | Ub (nU*64 bf16)
    const size_t need = ((size_t)nU + (size_t)B) * HH * sizeof(float)
                      + (size_t)nU * DD * sizeof(unsigned short);
    const int blocks = (B + WAVES_PER_BLOCK - 1) / WAVES_PER_BLOCK;

    if (ws_size >= need) {
        float* U  = (float*)d_ws;
        float* Ib = U + (size_t)nU * HH;
        unsigned short* Ub = (unsigned short*)(Ib + (size_t)B * HH);
        const int userBlocks = (nU + 255) / 256;
        const int itemBlocks = (B + 255) / 256;
        precompute_kernel<<<userBlocks + itemBlocks, 256, 0, stream>>>(
            user_table, item_table, item_inputs, att_w1, att_b1,
            U, Ib, Ub, nU, B, userBlocks);
        agree_main<<<blocks, 256, 0, stream>>>(
            group_inputs, item_inputs, member_ids, member_lengths,
            item_table, group_table,
            att_w2, att_b2, pred_w1, pred_b1, pred_w2, pred_b2,
            U, Ib, Ub, out, B);
    } else {
        agree_fallback<<<blocks, 256, 0, stream>>>(
            group_inputs, item_inputs, member_ids, member_lengths,
            user_table, item_table, group_table,
            att_w1, att_b1, att_w2, att_b2,
            pred_w1, pred_b1, pred_w2, pred_b2,
            out, B);
    }
}

// Round 8
// 143.364 us; speedup vs baseline: 1.2183x; 1.0131x over previous
//
#include <hip/hip_runtime.h>
#include <math.h>

constexpr int MM = 50;    // members per group
constexpr int DD = 64;    // embedding dim
constexpr int HH = 16;    // attention hidden
constexpr int PH = 8;     // predict hidden
constexpr int WAVES_PER_BLOCK = 4;
constexpr int SLOTS = 56; // 7 chunks x 8, zero-padded past member 49

// round-to-nearest-even fp32 -> bf16 (as uint16 in low bits)
__device__ __forceinline__ unsigned bf16rne(float f) {
    const unsigned u = __float_as_uint(f);
    return (u + 0x7FFFu + ((u >> 16) & 1u)) >> 16;
}

// ============================================================================
// Kernel A: Ubf = bf16(user_table @ W1a)            (nU x 16, packed pairs)
//           Ub  = bf16(user_table)                  (nU x 64)
//           Ib  = item_table[item_inputs] @ W1b + b1 (B x 16) fp32
// thread-per-row GEMV; branch uniform per block.
// ============================================================================
__global__ __launch_bounds__(256) void precompute_kernel(
    const float* __restrict__ user_table,
    const float* __restrict__ item_table,
    const int*   __restrict__ item_inputs,
    const float* __restrict__ att_w1,   // [2D][H] row-major
    const float* __restrict__ att_b1,   // [H]
    unsigned short* __restrict__ Ubf,   // bf16 U, dim pairs packed in uint
    float* __restrict__ Ib,
    unsigned short* __restrict__ Ub,    // bf16 user table copy
    int nU, int B, int userBlocks)
{
    const bool isU = (int)blockIdx.x < userBlocks;
    const float4* rp;
    const float*  w1;
    float acc[HH];
    int row = 0;

    if (isU) {
        row = (int)blockIdx.x * 256 + (int)threadIdx.x;
        if (row >= nU) return;
        rp  = (const float4*)(user_table + (size_t)row * DD);
        w1  = att_w1;
        #pragma unroll
        for (int j = 0; j < HH; ++j) acc[j] = 0.0f;
    } else {
        row = ((int)blockIdx.x - userBlocks) * 256 + (int)threadIdx.x;
        if (row >= B) return;
        const int item = item_inputs[row];
        rp  = (const float4*)(item_table + (size_t)item * DD);
        w1  = att_w1 + (size_t)DD * HH;
        #pragma unroll
        for (int j = 0; j < HH; ++j) acc[j] = att_b1[j];
    }

    unsigned brow[DD / 2];              // packed bf16 row (users only)

    #pragma unroll 4
    for (int d4 = 0; d4 < DD / 4; ++d4) {
        const float4 x = rp[d4];
        const float* w = w1 + (size_t)(d4 * 4) * HH;       // uniform -> s_load
        #pragma unroll
        for (int j = 0; j < HH; ++j) {
            acc[j] = fmaf(x.x, w[0 * HH + j], acc[j]);
            acc[j] = fmaf(x.y, w[1 * HH + j], acc[j]);
            acc[j] = fmaf(x.z, w[2 * HH + j], acc[j]);
            acc[j] = fmaf(x.w, w[3 * HH + j], acc[j]);
        }
        brow[2 * d4]     = bf16rne(x.x) | (bf16rne(x.y) << 16);
        brow[2 * d4 + 1] = bf16rne(x.z) | (bf16rne(x.w) << 16);
    }

    if (isU) {
        // U as bf16: word w packs dims (2w | 2w+1<<16); one 32B row store
        unsigned uw[8];
        #pragma unroll
        for (int w = 0; w < 8; ++w)
            uw[w] = bf16rne(acc[2 * w]) | (bf16rne(acc[2 * w + 1]) << 16);
        uint4* u4 = (uint4*)(Ubf + (size_t)row * HH);
        u4[0] = make_uint4(uw[0], uw[1], uw[2], uw[3]);
        u4[1] = make_uint4(uw[4], uw[5], uw[6], uw[7]);

        uint4* b4 = (uint4*)(Ub + (size_t)row * DD);       // 128B row
        #pragma unroll
        for (int i = 0; i < DD / 8; ++i)
            b4[i] = make_uint4(brow[4 * i], brow[4 * i + 1],
                               brow[4 * i + 2], brow[4 * i + 3]);
    } else {
        float4* o4 = (float4*)(Ib + (size_t)row * HH);
        o4[0] = make_float4(acc[0],  acc[1],  acc[2],  acc[3]);
        o4[1] = make_float4(acc[4],  acc[5],  acc[6],  acc[7]);
        o4[2] = make_float4(acc[8],  acc[9],  acc[10], acc[11]);
        o4[3] = make_float4(acc[12], acc[13], acc[14], acc[15]);
    }
}

// ============================================================================
// Kernel B: wave-per-row. Phase-1 U gather is bf16 (32B/lane); pool gathers
// bf16 rows (128B). Phase 1 once per row; chunks of 8 loads in flight.
// ============================================================================
__global__ __launch_bounds__(256) void agree_main(
    const int* __restrict__ group_inputs,
    const int* __restrict__ item_inputs,
    const int* __restrict__ member_ids,
    const int* __restrict__ member_lengths,
    const float* __restrict__ item_table,
    const float* __restrict__ group_table,
    const float* __restrict__ att_w2,   // [H]
    const float* __restrict__ att_b2,   // [1]
    const float* __restrict__ pred_w1,  // [3D][8]
    const float* __restrict__ pred_b1,  // [8]
    const float* __restrict__ pred_w2,  // [8]
    const float* __restrict__ pred_b2,  // [1]
    const unsigned short* __restrict__ Ubf, // [nU][16] bf16 pair-packed
    const float* __restrict__ Ib,       // [B][16], b1 folded
    const unsigned short* __restrict__ Ub, // [nU][64] bf16
    float* __restrict__ out,
    int B)
{
    __shared__ float2 pairs[WAVES_PER_BLOCK][SLOTS]; // (wnorm, id bits), 1792 B

    const int lane = threadIdx.x & 63;
    const int wv   = threadIdx.x >> 6;
    const int b    = blockIdx.x * WAVES_PER_BLOCK + wv;
    if (b >= B) return;

    const int my_m  = (lane < MM) ? lane : (MM - 1);
    const int my_id = member_ids[b * MM + my_m];            // coalesced
    const int len   = member_lengths[b];                    // uniform
    const int item_idx = item_inputs[b];                    // uniform
    const int gid      = group_inputs[b];                   // uniform

    // issue post-softmax rows early so they're in flight during phase 1
    const float item_d = item_table[(unsigned)(item_idx * DD + lane)];
    const float grp_d  = group_table[(unsigned)(gid * DD + lane)];

    // ---- phase 1: attention score, lane-per-member (bf16 U, 32B/lane)
    const uint4* up = (const uint4*)(Ubf + ((size_t)(unsigned)my_id * HH));
    const uint4 ua = up[0], ubw = up[1];
    const float* ib = Ib + (size_t)b * HH;                  // uniform -> s_load

    float score = att_b2[0];
    {
        const unsigned uw[8] = { ua.x, ua.y, ua.z, ua.w,
                                 ubw.x, ubw.y, ubw.z, ubw.w };
        #pragma unroll
        for (int w = 0; w < 8; ++w) {
            const float f0 = __uint_as_float(uw[w] << 16);          // dim 2w
            const float f1 = __uint_as_float(uw[w] & 0xFFFF0000u);  // dim 2w+1
            score = fmaf(fmaxf(f0 + ib[2 * w],     0.0f), att_w2[2 * w],     score);
            score = fmaf(fmaxf(f1 + ib[2 * w + 1], 0.0f), att_w2[2 * w + 1], score);
        }
    }

    const bool valid = (lane < MM) && (lane <= len);
    score = valid ? score : -INFINITY;

    // softmax over members (member 0 always valid)
    float mx = score;
    #pragma unroll
    for (int off = 32; off > 0; off >>= 1) mx = fmaxf(mx, __shfl_xor(mx, off, 64));
    const float e = valid ? __expf(score - mx) : 0.0f;
    float sum = e;
    #pragma unroll
    for (int off = 32; off > 0; off >>= 1) sum += __shfl_xor(sum, off, 64);
    const float wnorm = e / sum;    // 0 for invalid lanes (incl. 50..63)

    // stash (wnorm, id) pairs; slots 50..55 get wnorm=0 with a valid id
    if (lane < SLOTS) pairs[wv][lane] = make_float2(wnorm, __int_as_float(my_id));
    __builtin_amdgcn_s_waitcnt(0);  // drain own-wave LDS writes (no barrier)

    // ---- phase 2: weighted pool from bf16 table, chunks of 8 loads in flight
    const int mcnt   = (len < MM - 1 ? len : MM - 1) + 1;   // uniform in [1,50]
    const int chunks = (mcnt + 7) >> 3;                     // 1..7, uniform

    float g = 0.0f;
    for (int c = 0; c < chunks; ++c) {
        float2 q[8];
        #pragma unroll
        for (int k = 0; k < 8; ++k) q[k] = pairs[wv][c * 8 + k]; // broadcast reads
        unsigned short xb[8];
        #pragma unroll
        for (int k = 0; k < 8; ++k) {
            const unsigned idx = (unsigned)(__float_as_int(q[k].y) * DD + lane);
            xb[k] = Ub[idx];                                // 128B coalesced bf16 row
        }
        #pragma unroll
        for (int k = 0; k < 8; ++k)
            g = fmaf(q[k].x, __uint_as_float((unsigned)xb[k] << 16), g);
    }
    g += grp_d;

    // ---- predict MLP: new_e = [g*item, g, item] (192 -> 8 -> 1), lane-per-d
    const float elem = g * item_d;
    float p[PH];
    {
        const float* pa = pred_w1 + (size_t)lane * PH;      // L1-hot
        const float* pb = pred_w1 + (size_t)(DD + lane) * PH;
        const float* pc = pred_w1 + (size_t)(2 * DD + lane) * PH;
        #pragma unroll
        for (int j = 0; j < PH; ++j)
            p[j] = fmaf(elem, pa[j], fmaf(g, pb[j], item_d * pc[j]));
    }
    #pragma unroll
    for (int off = 32; off > 0; off >>= 1) {
        #pragma unroll
        for (int j = 0; j < PH; ++j) p[j] += __shfl_xor(p[j], off, 64);
    }

    if (lane == 0) {
        float acc = pred_b2[0];
        #pragma unroll
        for (int j = 0; j < PH; ++j)
            acc = fmaf(fmaxf(p[j] + pred_b1[j], 0.0f), pred_w2[j], acc);
        out[b] = 1.0f / (1.0f + __expf(-acc));
    }
}

// ============================================================================
// Fallback if ws too small (self-contained, round-2 structure, full fp32)
// ============================================================================
__global__ __launch_bounds__(256) void agree_fallback(
    const int* __restrict__ group_inputs,
    const int* __restrict__ item_inputs,
    const int* __restrict__ member_ids,
    const int* __restrict__ member_lengths,
    const float* __restrict__ user_table,
    const float* __restrict__ item_table,
    const float* __restrict__ group_table,
    const float* __restrict__ att_w1,
    const float* __restrict__ att_b1,
    const float* __restrict__ att_w2,
    const float* __restrict__ att_b2,
    const float* __restrict__ pred_w1,
    const float* __restrict__ pred_b1,
    const float* __restrict__ pred_w2,
    const float* __restrict__ pred_b2,
    float* __restrict__ out,
    int B)
{
    __shared__ float lds_wt[4][MM];
    __shared__ int   lds_id[4][MM];

    const int lane = threadIdx.x & 63;
    const int wave = threadIdx.x >> 6;
    const int b = blockIdx.x * 4 + wave;
    if (b >= B) return;

    const int my_m = (lane < MM) ? lane : (MM - 1);
    const int my_id = member_ids[b * MM + my_m];
    if (lane < MM) lds_id[wave][lane] = my_id;

    const int item_idx = item_inputs[b];
    const float item_d = item_table[(size_t)item_idx * DD + lane];

    float h[HH];
    {
        const float* w1row = att_w1 + (size_t)(DD + lane) * HH;
        #pragma unroll
        for (int j = 0; j < HH; ++j) h[j] = item_d * w1row[j];
        #pragma unroll
        for (int off = 32; off > 0; off >>= 1) {
            #pragma unroll
            for (int j = 0; j < HH; ++j) h[j] += __shfl_xor(h[j], off, 64);
        }
        #pragma unroll
        for (int j = 0; j < HH; ++j) h[j] += att_b1[j];
    }

    const float* myrow = user_table + (size_t)my_id * DD;
    #pragma unroll 4
    for (int d4 = 0; d4 < DD / 4; ++d4) {
        const float4 x = ((const float4*)myrow)[d4];
        const float* w1d = att_w1 + (size_t)(d4 * 4) * HH;
        #pragma unroll
        for (int j = 0; j < HH; ++j) {
            h[j] = fmaf(x.x, w1d[0 * HH + j], h[j]);
            h[j] = fmaf(x.y, w1d[1 * HH + j], h[j]);
            h[j] = fmaf(x.z, w1d[2 * HH + j], h[j]);
            h[j] = fmaf(x.w, w1d[3 * HH + j], h[j]);
        }
    }

    float score = att_b2[0];
    #pragma unroll
    for (int j = 0; j < HH; ++j) score = fmaf(fmaxf(h[j], 0.0f), att_w2[j], score);

    const int len = member_lengths[b];
    const bool valid = (lane < MM) && (lane <= len);
    score = valid ? score : -INFINITY;

    float mx = score;
    #pragma unroll
    for (int off = 32; off > 0; off >>= 1) mx = fmaxf(mx, __shfl_xor(mx, off, 64));
    float e = valid ? __expf(score - mx) : 0.0f;
    float sum = e;
    #pragma unroll
    for (int off = 32; off > 0; off >>= 1) sum += __shfl_xor(sum, off, 64);
    if (lane < MM) lds_wt[wave][lane] = e / sum;
    __builtin_amdgcn_s_waitcnt(0);

    const int mcnt = (len < MM - 1 ? len : MM - 1) + 1;
    float g = 0.0f;
    #pragma unroll 2
    for (int m = 0; m < mcnt; ++m) {
        g = fmaf(lds_wt[wave][m],
                 user_table[(size_t)lds_id[wave][m] * DD + lane], g);
    }
    const int gid = group_inputs[b];
    g += group_table[(size_t)gid * DD + lane];

    const float elem = g * item_d;
    float p[PH];
    {
        const float* pa = pred_w1 + (size_t)lane * PH;
        const float* pb = pred_w1 + (size_t)(DD + lane) * PH;
        const float* pc = pred_w1 + (size_t)(2 * DD + lane) * PH;
        #pragma unroll
        for (int j = 0; j < PH; ++j)
            p[j] = fmaf(elem, pa[j], fmaf(g, pb[j], item_d * pc[j]));
    }
    #pragma unroll
    for (int off = 32; off > 0; off >>= 1) {
        #pragma unroll
        for (int j = 0; j < PH; ++j) p[j] += __shfl_xor(p[j], off, 64);
    }

    if (lane == 0) {
        float acc = pred_b2[0];
        #pragma unroll
        for (int j = 0; j < PH; ++j)
            acc = fmaf(fmaxf(p[j] + pred_b1[j], 0.0f), pred_w2[j], acc);
        out[b] = 1.0f / (1.0f + __expf(-acc));
    }
}

extern "C" void kernel_launch(void* const* d_in, const int* in_sizes, int n_in,
                              void* d_out, int out_size, void* d_ws, size_t ws_size,
                              hipStream_t stream) {
    const int*   group_inputs   = (const int*)d_in[0];
    const int*   item_inputs    = (const int*)d_in[1];
    const int*   member_ids     = (const int*)d_in[2];
    const int*   member_lengths = (const int*)d_in[3];
    const float* user_table     = (const float*)d_in[4];
    const float* item_table     = (const float*)d_in[5];
    const float* group_table    = (const float*)d_in[6];
    const float* att_w1         = (const float*)d_in[7];
    const float* att_b1         = (const float*)d_in[8];
    const float* att_w2         = (const float*)d_in[9];
    const float* att_b2         = (const float*)d_in[10];
    const float* pred_w1        = (const float*)d_in[11];
    const float* pred_b1        = (const float*)d_in[12];
    const float* pred_w2        = (const float*)d_in[13];
    const float* pred_b2        = (const float*)d_in[14];
    float* out = (float*)d_out;

    const int B  = in_sizes[0];
    const int nU = in_sizes[4] / DD;
    // ws layout: Ubf (nU*16 bf16) | Ib (B*16 f32) | Ub (nU*64 bf16)
    const size_t need = (size_t)nU * HH * sizeof(unsigned short)
                      + (size_t)B  * HH * sizeof(float)
                      + (size_t)nU * DD * sizeof(unsigned short);
    const int blocks = (B + WAVES_PER_BLOCK - 1) / WAVES_PER_BLOCK;

    if (ws_size >= need) {
        unsigned short* Ubf = (unsigned short*)d_ws;
        float* Ib = (float*)(Ubf + (size_t)nU * HH);
        unsigned short* Ub = (unsigned short*)(Ib + (size_t)B * HH);
        const int userBlocks = (nU + 255) / 256;
        const int itemBlocks = (B + 255) / 256;
        precompute_kernel<<<userBlocks + itemBlocks, 256, 0, stream>>>(
            user_table, item_table, item_inputs, att_w1, att_b1,
            Ubf, Ib, Ub, nU, B, userBlocks);
        agree_main<<<blocks, 256, 0, stream>>>(
            group_inputs, item_inputs, member_ids, member_lengths,
            item_table, group_table,
            att_w2, att_b2, pred_w1, pred_b1, pred_w2, pred_b2,
            Ubf, Ib, Ub, out, B);
    } else {
        agree_fallback<<<blocks, 256, 0, stream>>>(
            group_inputs, item_inputs, member_ids, member_lengths,
            user_table, item_table, group_table,
            att_w1, att_b1, att_w2, att_b2,
            pred_w1, pred_b1, pred_w2, pred_b2,
            out, B);
    }
}